// Round 8
// baseline (84.450 us; speedup 1.0000x reference)
//
#include <hip/hip_runtime.h>
#include <hip/hip_bf16.h>
#include <stdint.h>

#define BATCH 8
#define SEQ   2048
#define EMB   1024
#define HD    128

typedef __attribute__((ext_vector_type(8))) short  s8v;
typedef __attribute__((ext_vector_type(4))) float  f4v;

__device__ __forceinline__ ushort cvt_bf16(float f) {
    union { float f; uint32_t u; } v; v.f = f;
    uint32_t r = v.u + 0x7FFFu + ((v.u >> 16) & 1u);
    return (ushort)(r >> 16);
}

__device__ __forceinline__ uint32_t pack_bf16(float lo, float hi) {
    return ((uint32_t)cvt_bf16(hi) << 16) | (uint32_t)cvt_bf16(lo);
}

__device__ __forceinline__ f4v mfma16(s8v a, s8v b, f4v c) {
    return __builtin_amdgcn_mfma_f32_16x16x32_bf16(a, b, c, 0, 0, 0);
}

__device__ __forceinline__ uint32_t bperm(int idx, uint32_t v) {
    return (uint32_t)__builtin_amdgcn_ds_bpermute(idx, (int)v);
}

// async global->LDS DMA, 16B per lane; LDS dest = wave-uniform base + lane*16
__device__ __forceinline__ void gl_lds16(const void* g, void* l) {
    __builtin_amdgcn_global_load_lds(
        (const __attribute__((address_space(1))) void*)g,
        (__attribute__((address_space(3))) void*)l, 16, 0, 0);
}

// ---------------- Stage 0: W -> bf16 concat [384][1024] ----------------------------
__global__ __launch_bounds__(256) void wcvt_kernel(
    const float* __restrict__ Wk, const float* __restrict__ Wq,
    const float* __restrict__ Wv, ushort* __restrict__ Wb)
{
    const int row = blockIdx.x;                 // 0..383
    const float* __restrict__ src =
        (row < 128) ? Wk + (size_t)row * EMB :
        (row < 256) ? Wq + (size_t)(row - 128) * EMB :
                      Wv + (size_t)(row - 256) * EMB;
    const int c = threadIdx.x << 2;
    float4 f = *(const float4*)(src + c);
    ushort4 h;
    h.x = cvt_bf16(f.x); h.y = cvt_bf16(f.y);
    h.z = cvt_bf16(f.z); h.w = cvt_bf16(f.w);
    *(ushort4*)(Wb + (size_t)row * EMB + c) = h;
}

// ---------------- Stage 1: QKV projection (M=64 tiles, 3 blocks/CU) ----------------
// grid = 768 (256 M-tiles x 3 weights), XCD-triplet-swizzled. 256 thr, 4 waves
// (2x2, wave-tile 32x64), BK=64, 2 barriers/step, VALU staging (x f32->bf16).
__global__ __launch_bounds__(256) void qkv_kernel(
    const float* __restrict__ x,
    const ushort* __restrict__ Wb,     // [384][1024] bf16 (K|Q|V)
    ushort* __restrict__ Kg,           // [B*T][128] bf16
    ushort* __restrict__ Qg,           // [B*T][128] bf16
    ushort* __restrict__ VTg)          // [B][128][T] bf16 (transposed)
{
    // bid = (mt&7) + 8*(3*(mt>>3) + wsel)  -> same XCD for a tile's 3 blocks
    const int bid  = blockIdx.x;
    const int rest = bid >> 3;
    const int wsel = rest % 3;                  // 0:K 1:Q 2:V
    const int mt   = ((rest / 3) << 3) | (bid & 7);
    const int m0 = mt * 64;
    const ushort* __restrict__ Wp = Wb + (size_t)wsel * 128 * EMB;

    __shared__ ushort Al[64][72];    // +8 pad
    __shared__ ushort Bl[128][72];

    const int tid  = threadIdx.x;
    const int lane = tid & 63;
    const int wave = tid >> 6;
    const int wm = wave >> 1, wn = wave & 1;
    const int lr = lane & 15, lg = lane >> 4;

    f4v acc[2][4] = {};

    // staging geometry (fixed per thread)
    const int xr = tid >> 2, xq = (tid & 3) << 4;     // x: row, col16
    const int wr = tid >> 1, wq = (tid & 1) << 5;     // W: row, col32

    for (int k0 = 0; k0 < EMB; k0 += 64) {
        {   // x: 64x64 f32 -> bf16
            const float* xp = x + (size_t)(m0 + xr) * EMB + k0 + xq;
            float4 f0 = *(const float4*)(xp);
            float4 f1 = *(const float4*)(xp + 4);
            float4 f2 = *(const float4*)(xp + 8);
            float4 f3 = *(const float4*)(xp + 12);
            ushort4 h;
            h.x = cvt_bf16(f0.x); h.y = cvt_bf16(f0.y);
            h.z = cvt_bf16(f0.z); h.w = cvt_bf16(f0.w);
            *(ushort4*)&Al[xr][xq] = h;
            h.x = cvt_bf16(f1.x); h.y = cvt_bf16(f1.y);
            h.z = cvt_bf16(f1.z); h.w = cvt_bf16(f1.w);
            *(ushort4*)&Al[xr][xq + 4] = h;
            h.x = cvt_bf16(f2.x); h.y = cvt_bf16(f2.y);
            h.z = cvt_bf16(f2.z); h.w = cvt_bf16(f2.w);
            *(ushort4*)&Al[xr][xq + 8] = h;
            h.x = cvt_bf16(f3.x); h.y = cvt_bf16(f3.y);
            h.z = cvt_bf16(f3.z); h.w = cvt_bf16(f3.w);
            *(ushort4*)&Al[xr][xq + 12] = h;
        }
        {   // W: 128x64 bf16 copy
            const ushort* wp = Wp + (size_t)wr * EMB + k0 + wq;
            *(int4*)&Bl[wr][wq]      = *(const int4*)(wp);
            *(int4*)&Bl[wr][wq + 8]  = *(const int4*)(wp + 8);
            *(int4*)&Bl[wr][wq + 16] = *(const int4*)(wp + 16);
            *(int4*)&Bl[wr][wq + 24] = *(const int4*)(wp + 24);
        }
        __syncthreads();
        #pragma unroll
        for (int kk = 0; kk < 2; ++kk) {
            s8v af[2], bf[4];
            #pragma unroll
            for (int i = 0; i < 2; ++i)
                af[i] = *(const s8v*)&Al[32 * wm + 16 * i + lr][32 * kk + 8 * lg];
            #pragma unroll
            for (int j = 0; j < 4; ++j)
                bf[j] = *(const s8v*)&Bl[64 * wn + 16 * j + lr][32 * kk + 8 * lg];
            #pragma unroll
            for (int i = 0; i < 2; ++i)
                #pragma unroll
                for (int j = 0; j < 4; ++j)
                    acc[i][j] = mfma16(af[i], bf[j], acc[i][j]);
        }
        __syncthreads();
    }

    if (wsel < 2) {
        ushort* __restrict__ outp = wsel ? Qg : Kg;
        #pragma unroll
        for (int i = 0; i < 2; ++i)
            #pragma unroll
            for (int j = 0; j < 4; ++j) {
                int h = 64 * wn + 16 * j + lr;
                #pragma unroll
                for (int reg = 0; reg < 4; ++reg) {
                    int m = m0 + 32 * wm + 16 * i + 4 * lg + reg;
                    outp[(size_t)m * HD + h] = cvt_bf16(acc[i][j][reg]);
                }
            }
    } else {
        // V^T: lane's 4 regs are 4 consecutive t at fixed h -> one ushort4 store
        int bidx = m0 >> 11;
        int tb   = m0 & 2047;
        #pragma unroll
        for (int i = 0; i < 2; ++i)
            #pragma unroll
            for (int j = 0; j < 4; ++j) {
                int h = 64 * wn + 16 * j + lr;
                int t = tb + 32 * wm + 16 * i + 4 * lg;
                ushort4 hv;
                hv.x = cvt_bf16(acc[i][j][0]);
                hv.y = cvt_bf16(acc[i][j][1]);
                hv.z = cvt_bf16(acc[i][j][2]);
                hv.w = cvt_bf16(acc[i][j][3]);
                *(ushort4*)(VTg + ((size_t)bidx * HD + h) * SEQ + t) = hv;
            }
    }
}

// ---------------- Stage 2: flash attention, split-KV, dbuf gload_lds ---------------
// grid = (tri_slots, BATCH). Exact triangular decomposition; no dead blocks.
// Double-buffered K/V via global_load_lds + XOR swizzle; 1 barrier per tile.
__global__ __launch_bounds__(256) void attn_kernel(
    const ushort* __restrict__ Qg,
    const ushort* __restrict__ Kg,
    const ushort* __restrict__ VTg,
    ushort* __restrict__ o_part,     // [B*32*NCH*64][128] bf16, unnormalized
    float2* __restrict__ ml_part,    // [B*32*NCH*64] (m,l)
    int cts, int NCH)
{
    // decode triangular slot -> (jq, ch)
    int s = blockIdx.x, g = 0;
    while (s >= ((g + 1) << cts)) { s -= (g + 1) << cts; ++g; }
    int q2 = 0;
    while (s >= g + 1) { s -= g + 1; ++q2; }
    const int jq = (g << cts) + q2;
    const int ch = s;
    const int b  = blockIdx.y;
    const int t0 = ch << cts;
    const int t1 = min(t0 + (1 << cts), jq + 1);

    const int tid  = threadIdx.x;
    const int lane = tid & 63;
    const int wave = tid >> 6;
    const int lr = lane & 15, lg = lane >> 4;
    const int xsw = (lr & 7) << 4;

    __shared__ ushort kl[2][64 * 128];   // [s][d] linear, swizzled storage
    __shared__ ushort vl[2][128 * 64];   // [h][s] linear, swizzled storage

    const ushort* __restrict__ Qb = Qg  + (size_t)b * SEQ * HD;
    const ushort* __restrict__ Kb = Kg  + (size_t)b * SEQ * HD;
    const ushort* __restrict__ Vb = VTg + (size_t)b * HD * SEQ;

    // staging source pointers (inverse-swizzled so linear DMA lands swizzled)
    const char* gK[4];
    const char* gV[4];
    #pragma unroll
    for (int c = 0; c < 4; ++c) {
        int cc = wave * 4 + c;
        {   int row  = cc * 4 + (lane >> 4);                 // K: 4 rows/call
            int colb = ((lane & 15) << 4) ^ ((row & 7) << 4);
            gK[c] = (const char*)Kb + (size_t)(t0 * 64 + row) * 256 + colb; }
        {   int row  = cc * 8 + (lane >> 3);                 // V: 8 rows/call
            int colb = ((lane & 7) << 4) ^ ((row & 7) << 4);
            gV[c] = (const char*)Vb + (size_t)row * (SEQ * 2)
                    + (size_t)t0 * 128 + colb; }
    }

    const int qw    = jq * 64 + wave * 16;
    const int q_abs = qw + lr;

    s8v qf[4];
    #pragma unroll
    for (int f = 0; f < 4; ++f)
        qf[f] = *(const s8v*)(Qb + (size_t)(qw + lr) * HD + 32 * f + 8 * lg);

    f4v o[8] = {};
    float m_r = -1e30f, l_r = 0.0f;

    // prologue: stage tile t0 into buf 0
    #pragma unroll
    for (int c = 0; c < 4; ++c) {
        gl_lds16(gK[c], (char*)(&kl[0][0]) + ((wave * 4 + c) << 10));
        gl_lds16(gV[c], (char*)(&vl[0][0]) + ((wave * 4 + c) << 10));
        gK[c] += 64 * 256;
        gV[c] += 128;
    }
    __syncthreads();

    const int i0 = ((2 * (lg & 1)) * 16 + lr) << 2;
    const int i1 = ((2 * (lg & 1) + 1) * 16 + lr) << 2;
    const bool hi = (lg >= 2);

    int cur = 0;
    for (int st = t0; st < t1; ++st) {
        if (st + 1 < t1) {                       // issue next-tile DMA (T3/T4)
            char* kb = (char*)(&kl[cur ^ 1][0]);
            char* vb = (char*)(&vl[cur ^ 1][0]);
            #pragma unroll
            for (int c = 0; c < 4; ++c) {
                gl_lds16(gK[c], kb + ((wave * 4 + c) << 10));
                gl_lds16(gV[c], vb + ((wave * 4 + c) << 10));
                gK[c] += 64 * 256;
                gV[c] += 128;
            }
        }
        const int s0 = st * 64;
        const char* klb = (const char*)(&kl[cur][0]);
        const char* vlb = (const char*)(&vl[cur][0]);

        // QK^T (swapped): lane owns q-col q_abs, holds s rows
        f4v sc[4] = {};
        #pragma unroll
        for (int sf = 0; sf < 4; ++sf)
            #pragma unroll
            for (int kf = 0; kf < 4; ++kf) {
                s8v kfr = *(const s8v*)(klb + ((sf * 16 + lr) << 8)
                                        + ((kf * 64 + lg * 16) ^ xsw));
                sc[sf] = mfma16(kfr, qf[kf], sc[sf]);
            }

        float p[4][4];
        const bool diag = (st == jq);
        #pragma unroll
        for (int sf = 0; sf < 4; ++sf)
            #pragma unroll
            for (int reg = 0; reg < 4; ++reg) {
                float v = sc[sf][reg] * 0.03125f;          // C^-0.5 = 1/32
                if (diag && (s0 + sf * 16 + 4 * lg + reg) > q_abs) v = -1e30f;
                p[sf][reg] = v;
            }

        // online softmax: in-lane (16) + 2 shuffles across lg quads
        float pm = p[0][0];
        #pragma unroll
        for (int sf = 0; sf < 4; ++sf)
            #pragma unroll
            for (int reg = 0; reg < 4; ++reg) pm = fmaxf(pm, p[sf][reg]);
        pm = fmaxf(pm, __shfl_xor(pm, 16));
        pm = fmaxf(pm, __shfl_xor(pm, 32));
        const float mnew = fmaxf(m_r, pm);
        const float fac  = __expf(m_r - mnew);
        m_r = mnew;

        float ls = 0.0f;
        #pragma unroll
        for (int sf = 0; sf < 4; ++sf)
            #pragma unroll
            for (int reg = 0; reg < 4; ++reg) {
                p[sf][reg] = __expf(p[sf][reg] - mnew);
                ls += p[sf][reg];
            }
        ls += __shfl_xor(ls, 16);
        ls += __shfl_xor(ls, 32);
        l_r = l_r * fac + ls;
        #pragma unroll
        for (int hf = 0; hf < 8; ++hf) o[hf] *= fac;

        // pack P -> bf16 pairs; redistribute to PV B-fragments via bpermute
        uint32_t pk[4][2];
        #pragma unroll
        for (int sf = 0; sf < 4; ++sf) {
            pk[sf][0] = pack_bf16(p[sf][0], p[sf][1]);
            pk[sf][1] = pack_bf16(p[sf][2], p[sf][3]);
        }

        #pragma unroll
        for (int s2 = 0; s2 < 2; ++s2) {
            uint32_t a0 = bperm(i0, pk[2 * s2][0]);
            uint32_t a1 = bperm(i0, pk[2 * s2][1]);
            uint32_t a2 = bperm(i1, pk[2 * s2][0]);
            uint32_t a3 = bperm(i1, pk[2 * s2][1]);
            uint32_t b0 = bperm(i0, pk[2 * s2 + 1][0]);
            uint32_t b1 = bperm(i0, pk[2 * s2 + 1][1]);
            uint32_t b2 = bperm(i1, pk[2 * s2 + 1][0]);
            uint32_t b3 = bperm(i1, pk[2 * s2 + 1][1]);
            union { int4 i; s8v h; } pb;
            pb.i.x = (int)(hi ? b0 : a0);
            pb.i.y = (int)(hi ? b1 : a1);
            pb.i.z = (int)(hi ? b2 : a2);
            pb.i.w = (int)(hi ? b3 : a3);
            #pragma unroll
            for (int hf = 0; hf < 8; ++hf) {
                s8v vf = *(const s8v*)(vlb + ((hf * 16 + lr) << 7)
                                       + ((s2 * 64 + lg * 16) ^ xsw));
                o[hf] = mfma16(vf, pb.h, o[hf]);
            }
        }

        __syncthreads();     // drains next-tile DMA (vmcnt) + all LDS reads
        cur ^= 1;
    }

    // write unnormalized partial + (m,l)
    const size_t pbase = ((size_t)(b * 32 + jq) * NCH + ch) * 64;
    const int q = wave * 16 + lr;
    if (lg == 0) {
        float2 v; v.x = m_r; v.y = l_r;
        ml_part[pbase + q] = v;
    }
    #pragma unroll
    for (int hf = 0; hf < 8; ++hf) {
        ushort4 hv;
        hv.x = cvt_bf16(o[hf][0]);
        hv.y = cvt_bf16(o[hf][1]);
        hv.z = cvt_bf16(o[hf][2]);
        hv.w = cvt_bf16(o[hf][3]);
        *(ushort4*)(o_part + (pbase + q) * HD + hf * 16 + 4 * lg) = hv;
    }
}

// ---------------- Stage 3: combine partials ---------------------------------------
// grid = 1024; block = 16 rows x 16 lanes/row (8 cols each).
__global__ __launch_bounds__(256) void combine_kernel(
    const ushort* __restrict__ o_part,
    const float2* __restrict__ ml_part,
    float* __restrict__ out, int cts, int NCH)
{
    const int tid = threadIdx.x;
    const int R   = blockIdx.x * 16 + (tid >> 4);    // global q-row 0..16383
    const int c16 = tid & 15;
    const int b  = R >> 11;
    const int rq = R & 2047;
    const int jq = rq >> 6;
    const int r  = rq & 63;
    const int nch = (jq >> cts) + 1;

    const size_t mlbase = ((size_t)(b * 32 + jq) * NCH) * 64 + r;

    float M = -1e30f;
    for (int c = 0; c < nch; ++c)
        M = fmaxf(M, ml_part[mlbase + (size_t)c * 64].x);
    float L = 0.0f;
    for (int c = 0; c < nch; ++c) {
        float2 v = ml_part[mlbase + (size_t)c * 64];
        L += v.y * __expf(v.x - M);
    }
    const float invL = 1.0f / L;

    float acc[8];
    #pragma unroll
    for (int k = 0; k < 8; ++k) acc[k] = 0.0f;

    for (int c = 0; c < nch; ++c) {
        float2 v = ml_part[mlbase + (size_t)c * 64];
        float sc = __expf(v.x - M) * invL;
        s8v pv = *(const s8v*)(o_part + (mlbase + (size_t)c * 64) * HD + c16 * 8);
        #pragma unroll
        for (int j = 0; j < 8; ++j) {
            union { uint32_t u; float f; } cv;
            cv.u = ((uint32_t)(ushort)pv[j]) << 16;
            acc[j] += cv.f * sc;
        }
    }

    float* po = out + (size_t)R * HD + c16 * 8;
    *(float4*)(po)     = make_float4(acc[0], acc[1], acc[2], acc[3]);
    *(float4*)(po + 4) = make_float4(acc[4], acc[5], acc[6], acc[7]);
}

extern "C" void kernel_launch(void* const* d_in, const int* in_sizes, int n_in,
                              void* d_out, int out_size, void* d_ws, size_t ws_size,
                              hipStream_t stream) {
    const float* x  = (const float*)d_in[0];
    const float* Wk = (const float*)d_in[1];
    const float* Wq = (const float*)d_in[2];
    const float* Wv = (const float*)d_in[3];

    const size_t qkv_elems = (size_t)BATCH * SEQ * HD;   // 2,097,152
    const size_t wb_elems  = (size_t)384 * EMB;          // 393,216
    ushort* Kg  = (ushort*)d_ws;
    ushort* Qg  = Kg + qkv_elems;
    ushort* VTg = Qg + qkv_elems;
    float*  outp = (float*)d_out;

    int cts = 2, NCH = 8;     // chunk = 4 kv-tiles (256 cols)
    {
        size_t rows = (size_t)BATCH * 32 * NCH * 64;
        size_t need = 3 * qkv_elems * sizeof(ushort)
                    + rows * (HD * sizeof(ushort) + sizeof(float2))
                    + wb_elems * sizeof(ushort);
        if (ws_size < need) { cts = 3; NCH = 4; }
    }
    size_t part_rows = (size_t)BATCH * 32 * NCH * 64;
    ushort* o_part  = VTg + qkv_elems;
    float2* ml_part = (float2*)(o_part + part_rows * HD);
    ushort* Wb      = (ushort*)(ml_part + part_rows);

    // triangular slot count: G groups of (1<<cts) jq's, group g has g+1 chunks
    const int G = 32 >> cts;
    const int slots = (1 << cts) * G * (G + 1) / 2;      // 144 (cts=2) / 80 (cts=3)

    wcvt_kernel<<<384, 256, 0, stream>>>(Wk, Wq, Wv, Wb);
    qkv_kernel<<<768, 256, 0, stream>>>(x, Wb, Kg, Qg, VTg);
    dim3 g2(slots, BATCH);
    attn_kernel<<<g2, 256, 0, stream>>>(Qg, Kg, VTg, o_part, ml_part, cts, NCH);
    combine_kernel<<<1024, 256, 0, stream>>>(o_part, ml_part, outp, cts, NCH);
}

// Round 9
// 82.755 us; speedup vs baseline: 1.0205x; 1.0205x over previous
//
#include <hip/hip_runtime.h>
#include <hip/hip_bf16.h>
#include <stdint.h>

#define BATCH 8
#define SEQ   2048
#define EMB   1024
#define HD    128

typedef __attribute__((ext_vector_type(8))) short  s8v;
typedef __attribute__((ext_vector_type(4))) float  f4v;

__device__ __forceinline__ ushort cvt_bf16(float f) {
    union { float f; uint32_t u; } v; v.f = f;
    uint32_t r = v.u + 0x7FFFu + ((v.u >> 16) & 1u);
    return (ushort)(r >> 16);
}

__device__ __forceinline__ uint32_t pack_bf16(float lo, float hi) {
    return ((uint32_t)cvt_bf16(hi) << 16) | (uint32_t)cvt_bf16(lo);
}

__device__ __forceinline__ f4v mfma16(s8v a, s8v b, f4v c) {
    return __builtin_amdgcn_mfma_f32_16x16x32_bf16(a, b, c, 0, 0, 0);
}

__device__ __forceinline__ uint32_t bperm(int idx, uint32_t v) {
    return (uint32_t)__builtin_amdgcn_ds_bpermute(idx, (int)v);
}

// async global->LDS DMA, 16B per lane; LDS dest = wave-uniform base + lane*16
__device__ __forceinline__ void gl_lds16(const void* g, void* l) {
    __builtin_amdgcn_global_load_lds(
        (const __attribute__((address_space(1))) void*)g,
        (__attribute__((address_space(3))) void*)l, 16, 0, 0);
}

// 8 f32 -> 8 bf16 packed (v_cvt_pk_bf16_f32)
__device__ __forceinline__ s8v cvt8(float4 a, float4 b) {
    union { s8v h; __hip_bfloat162 p[4]; } u;
    u.p[0] = __float22bfloat162_rn(make_float2(a.x, a.y));
    u.p[1] = __float22bfloat162_rn(make_float2(a.z, a.w));
    u.p[2] = __float22bfloat162_rn(make_float2(b.x, b.y));
    u.p[3] = __float22bfloat162_rn(make_float2(b.z, b.w));
    return u.h;
}

// ---------------- Stage 0: W -> bf16 concat [384][1024] ----------------------------
__global__ __launch_bounds__(256) void wcvt_kernel(
    const float* __restrict__ Wk, const float* __restrict__ Wq,
    const float* __restrict__ Wv, ushort* __restrict__ Wb)
{
    const int row = blockIdx.x;                 // 0..383
    const float* __restrict__ src =
        (row < 128) ? Wk + (size_t)row * EMB :
        (row < 256) ? Wq + (size_t)(row - 128) * EMB :
                      Wv + (size_t)(row - 256) * EMB;
    const int c = threadIdx.x << 2;
    float4 f = *(const float4*)(src + c);
    ushort4 h;
    h.x = cvt_bf16(f.x); h.y = cvt_bf16(f.y);
    h.z = cvt_bf16(f.z); h.w = cvt_bf16(f.w);
    *(ushort4*)(Wb + (size_t)row * EMB + c) = h;
}

// ---------------- Stage 1: QKV projection (r6 pipeline @ BM=128,BN=192) ------------
// grid = 256 (128 M-tiles x 2 N-halves), 512 thr (8 waves, 2m x 4n, wave 64x48).
// BK=64; W panel (192x64) via swizzled global_load_lds dbuf; x tile (128x64)
// via reg->cvt->swizzled ds_write dbuf. One barrier per k-step. LDS 80 KB ->
// 2 blocks/CU. XCD swizzle pairs the two nt-blocks of an mt (x shared in L2).
__global__ __launch_bounds__(512) void qkv_kernel(
    const float* __restrict__ x,
    const ushort* __restrict__ Wb,     // [384][1024] bf16 (K|Q|V)
    ushort* __restrict__ Kg,           // [B*T][128] bf16
    ushort* __restrict__ Qg,           // [B*T][128] bf16
    ushort* __restrict__ VTg)          // [B][128][T] bf16 (transposed)
{
    // bid = (mt&7) + 8*(2*(mt>>3) + nt) -> same XCD for a tile's 2 blocks
    const int bid  = blockIdx.x;
    const int rest = bid >> 3;
    const int nt   = rest & 1;
    const int mt   = ((rest >> 1) << 3) | (bid & 7);
    const int m0 = mt * 128;
    const int n0 = nt * 192;

    __shared__ ushort Asm[2][128 * 64];   // x tile, swizzled storage (16 KB each)
    __shared__ ushort Bsm[2][192 * 64];   // W panel, swizzled storage (24 KB each)

    const int tid  = threadIdx.x;
    const int lane = tid & 63;
    const int wave = tid >> 6;
    const int wm = wave >> 2, wn = wave & 3;
    const int lr = lane & 15, lg = lane >> 4;

    f4v acc[4][3] = {};

    // B DMA source pointers (inverse-swizzled): 3 chunks of 1KB per wave
    const char* gB[3];
    #pragma unroll
    for (int c = 0; c < 3; ++c) {
        int cc  = wave * 3 + c;
        int row = n0 + cc * 8 + (lane >> 3);        // row&7 == lane>>3
        int cg  = (lane & 7) ^ (lane >> 3);         // swizzled col granule
        gB[c] = (const char*)Wb + (size_t)row * (EMB * 2) + cg * 16;
    }
    // x: thread covers row tid>>2, 16 f32 at col (tid&3)*16
    const int ar = tid >> 2, aq = tid & 3;
    const float* xp = x + (size_t)(m0 + ar) * EMB + aq * 16;
    const int aw0 = ar * 128 + ((((aq << 1))     ^ (ar & 7)) << 4);
    const int aw1 = ar * 128 + ((((aq << 1) | 1) ^ (ar & 7)) << 4);

    // prologue: stage k-step 0 into buf 0
    #pragma unroll
    for (int c = 0; c < 3; ++c)
        gl_lds16(gB[c], (char*)(&Bsm[0][0]) + ((wave * 3 + c) << 10));
    {
        float4 f0 = *(const float4*)(xp);
        float4 f1 = *(const float4*)(xp + 4);
        float4 f2 = *(const float4*)(xp + 8);
        float4 f3 = *(const float4*)(xp + 12);
        *(s8v*)((char*)(&Asm[0][0]) + aw0) = cvt8(f0, f1);
        *(s8v*)((char*)(&Asm[0][0]) + aw1) = cvt8(f2, f3);
    }
    __syncthreads();

    int cur = 0;
    for (int st = 0; st < 16; ++st) {
        const bool more = (st + 1 < 16);
        float4 f0, f1, f2, f3;
        if (more) {
            #pragma unroll
            for (int c = 0; c < 3; ++c) {
                gB[c] += 128;                        // next 64 cols * 2B
                gl_lds16(gB[c], (char*)(&Bsm[cur ^ 1][0]) + ((wave * 3 + c) << 10));
            }
            const float* xn = xp + (st + 1) * 64;
            f0 = *(const float4*)(xn);
            f1 = *(const float4*)(xn + 4);
            f2 = *(const float4*)(xn + 8);
            f3 = *(const float4*)(xn + 12);
        }

        const char* Ab = (const char*)(&Asm[cur][0]);
        const char* Bb = (const char*)(&Bsm[cur][0]);
        #pragma unroll
        for (int kk = 0; kk < 2; ++kk) {
            s8v af[4], bf[3];
            #pragma unroll
            for (int i = 0; i < 4; ++i) {
                int r = 64 * wm + 16 * i + lr;
                af[i] = *(const s8v*)(Ab + r * 128 + ((((kk << 2) + lg) ^ (r & 7)) << 4));
            }
            #pragma unroll
            for (int j = 0; j < 3; ++j) {
                int r = 48 * wn + 16 * j + lr;
                bf[j] = *(const s8v*)(Bb + r * 128 + ((((kk << 2) + lg) ^ (r & 7)) << 4));
            }
            #pragma unroll
            for (int i = 0; i < 4; ++i)
                #pragma unroll
                for (int j = 0; j < 3; ++j)
                    acc[i][j] = mfma16(af[i], bf[j], acc[i][j]);
        }

        if (more) {
            char* An = (char*)(&Asm[cur ^ 1][0]);
            *(s8v*)(An + aw0) = cvt8(f0, f1);
            *(s8v*)(An + aw1) = cvt8(f2, f3);
        }
        __syncthreads();    // drains B-DMA (vmcnt) + A ds_writes; buffers flip
        cur ^= 1;
    }

    const int b  = m0 >> 11;
    const int tb = m0 & 2047;
    #pragma unroll
    for (int j = 0; j < 3; ++j) {
        const int n   = n0 + 48 * wn + 16 * j + lr;
        const int sel = n >> 7;                      // 0:K 1:Q 2:V
        const int h   = n & 127;
        if (sel < 2) {
            ushort* __restrict__ outp = sel ? Qg : Kg;
            #pragma unroll
            for (int i = 0; i < 4; ++i)
                #pragma unroll
                for (int reg = 0; reg < 4; ++reg) {
                    int m = m0 + 64 * wm + 16 * i + 4 * lg + reg;
                    outp[(size_t)m * HD + h] = cvt_bf16(acc[i][j][reg]);
                }
        } else {
            #pragma unroll
            for (int i = 0; i < 4; ++i) {
                int t = tb + 64 * wm + 16 * i + 4 * lg;
                ushort4 hv;
                hv.x = cvt_bf16(acc[i][j][0]);
                hv.y = cvt_bf16(acc[i][j][1]);
                hv.z = cvt_bf16(acc[i][j][2]);
                hv.w = cvt_bf16(acc[i][j][3]);
                *(ushort4*)(VTg + ((size_t)b * HD + h) * SEQ + t) = hv;
            }
        }
    }
}

// ---------------- Stage 2: flash attention, split-KV, dbuf gload_lds ---------------
// grid = (tri_slots, BATCH). Exact triangular decomposition; no dead blocks.
// Double-buffered K/V via global_load_lds + XOR swizzle; 1 barrier per tile.
__global__ __launch_bounds__(256) void attn_kernel(
    const ushort* __restrict__ Qg,
    const ushort* __restrict__ Kg,
    const ushort* __restrict__ VTg,
    ushort* __restrict__ o_part,     // [B*32*NCH*64][128] bf16, unnormalized
    float2* __restrict__ ml_part,    // [B*32*NCH*64] (m,l)
    int cts, int NCH)
{
    // decode triangular slot -> (jq, ch)
    int s = blockIdx.x, g = 0;
    while (s >= ((g + 1) << cts)) { s -= (g + 1) << cts; ++g; }
    int q2 = 0;
    while (s >= g + 1) { s -= g + 1; ++q2; }
    const int jq = (g << cts) + q2;
    const int ch = s;
    const int b  = blockIdx.y;
    const int t0 = ch << cts;
    const int t1 = min(t0 + (1 << cts), jq + 1);

    const int tid  = threadIdx.x;
    const int lane = tid & 63;
    const int wave = tid >> 6;
    const int lr = lane & 15, lg = lane >> 4;
    const int xsw = (lr & 7) << 4;

    __shared__ ushort kl[2][64 * 128];   // [s][d] linear, swizzled storage
    __shared__ ushort vl[2][128 * 64];   // [h][s] linear, swizzled storage

    const ushort* __restrict__ Qb = Qg  + (size_t)b * SEQ * HD;
    const ushort* __restrict__ Kb = Kg  + (size_t)b * SEQ * HD;
    const ushort* __restrict__ Vb = VTg + (size_t)b * HD * SEQ;

    // staging source pointers (inverse-swizzled so linear DMA lands swizzled)
    const char* gK[4];
    const char* gV[4];
    #pragma unroll
    for (int c = 0; c < 4; ++c) {
        int cc = wave * 4 + c;
        {   int row  = cc * 4 + (lane >> 4);                 // K: 4 rows/call
            int colb = ((lane & 15) << 4) ^ ((row & 7) << 4);
            gK[c] = (const char*)Kb + (size_t)(t0 * 64 + row) * 256 + colb; }
        {   int row  = cc * 8 + (lane >> 3);                 // V: 8 rows/call
            int colb = ((lane & 7) << 4) ^ ((row & 7) << 4);
            gV[c] = (const char*)Vb + (size_t)row * (SEQ * 2)
                    + (size_t)t0 * 128 + colb; }
    }

    const int qw    = jq * 64 + wave * 16;
    const int q_abs = qw + lr;

    s8v qf[4];
    #pragma unroll
    for (int f = 0; f < 4; ++f)
        qf[f] = *(const s8v*)(Qb + (size_t)(qw + lr) * HD + 32 * f + 8 * lg);

    f4v o[8] = {};
    float m_r = -1e30f, l_r = 0.0f;

    // prologue: stage tile t0 into buf 0
    #pragma unroll
    for (int c = 0; c < 4; ++c) {
        gl_lds16(gK[c], (char*)(&kl[0][0]) + ((wave * 4 + c) << 10));
        gl_lds16(gV[c], (char*)(&vl[0][0]) + ((wave * 4 + c) << 10));
        gK[c] += 64 * 256;
        gV[c] += 128;
    }
    __syncthreads();

    const int i0 = ((2 * (lg & 1)) * 16 + lr) << 2;
    const int i1 = ((2 * (lg & 1) + 1) * 16 + lr) << 2;
    const bool hi = (lg >= 2);

    int cur = 0;
    for (int st = t0; st < t1; ++st) {
        if (st + 1 < t1) {                       // issue next-tile DMA (T3/T4)
            char* kb = (char*)(&kl[cur ^ 1][0]);
            char* vb = (char*)(&vl[cur ^ 1][0]);
            #pragma unroll
            for (int c = 0; c < 4; ++c) {
                gl_lds16(gK[c], kb + ((wave * 4 + c) << 10));
                gl_lds16(gV[c], vb + ((wave * 4 + c) << 10));
                gK[c] += 64 * 256;
                gV[c] += 128;
            }
        }
        const int s0 = st * 64;
        const char* klb = (const char*)(&kl[cur][0]);
        const char* vlb = (const char*)(&vl[cur][0]);

        // QK^T (swapped): lane owns q-col q_abs, holds s rows
        f4v sc[4] = {};
        #pragma unroll
        for (int sf = 0; sf < 4; ++sf)
            #pragma unroll
            for (int kf = 0; kf < 4; ++kf) {
                s8v kfr = *(const s8v*)(klb + ((sf * 16 + lr) << 8)
                                        + ((kf * 64 + lg * 16) ^ xsw));
                sc[sf] = mfma16(kfr, qf[kf], sc[sf]);
            }

        float p[4][4];
        const bool diag = (st == jq);
        #pragma unroll
        for (int sf = 0; sf < 4; ++sf)
            #pragma unroll
            for (int reg = 0; reg < 4; ++reg) {
                float v = sc[sf][reg] * 0.03125f;          // C^-0.5 = 1/32
                if (diag && (s0 + sf * 16 + 4 * lg + reg) > q_abs) v = -1e30f;
                p[sf][reg] = v;
            }

        // online softmax: in-lane (16) + 2 shuffles across lg quads
        float pm = p[0][0];
        #pragma unroll
        for (int sf = 0; sf < 4; ++sf)
            #pragma unroll
            for (int reg = 0; reg < 4; ++reg) pm = fmaxf(pm, p[sf][reg]);
        pm = fmaxf(pm, __shfl_xor(pm, 16));
        pm = fmaxf(pm, __shfl_xor(pm, 32));
        const float mnew = fmaxf(m_r, pm);
        const float fac  = __expf(m_r - mnew);
        m_r = mnew;

        float ls = 0.0f;
        #pragma unroll
        for (int sf = 0; sf < 4; ++sf)
            #pragma unroll
            for (int reg = 0; reg < 4; ++reg) {
                p[sf][reg] = __expf(p[sf][reg] - mnew);
                ls += p[sf][reg];
            }
        ls += __shfl_xor(ls, 16);
        ls += __shfl_xor(ls, 32);
        l_r = l_r * fac + ls;
        #pragma unroll
        for (int hf = 0; hf < 8; ++hf) o[hf] *= fac;

        // pack P -> bf16 pairs; redistribute to PV B-fragments via bpermute
        uint32_t pk[4][2];
        #pragma unroll
        for (int sf = 0; sf < 4; ++sf) {
            pk[sf][0] = pack_bf16(p[sf][0], p[sf][1]);
            pk[sf][1] = pack_bf16(p[sf][2], p[sf][3]);
        }

        #pragma unroll
        for (int s2 = 0; s2 < 2; ++s2) {
            uint32_t a0 = bperm(i0, pk[2 * s2][0]);
            uint32_t a1 = bperm(i0, pk[2 * s2][1]);
            uint32_t a2 = bperm(i1, pk[2 * s2][0]);
            uint32_t a3 = bperm(i1, pk[2 * s2][1]);
            uint32_t b0 = bperm(i0, pk[2 * s2 + 1][0]);
            uint32_t b1 = bperm(i0, pk[2 * s2 + 1][1]);
            uint32_t b2 = bperm(i1, pk[2 * s2 + 1][0]);
            uint32_t b3 = bperm(i1, pk[2 * s2 + 1][1]);
            union { int4 i; s8v h; } pb;
            pb.i.x = (int)(hi ? b0 : a0);
            pb.i.y = (int)(hi ? b1 : a1);
            pb.i.z = (int)(hi ? b2 : a2);
            pb.i.w = (int)(hi ? b3 : a3);
            #pragma unroll
            for (int hf = 0; hf < 8; ++hf) {
                s8v vf = *(const s8v*)(vlb + ((hf * 16 + lr) << 7)
                                       + ((s2 * 64 + lg * 16) ^ xsw));
                o[hf] = mfma16(vf, pb.h, o[hf]);
            }
        }

        __syncthreads();     // drains next-tile DMA (vmcnt) + all LDS reads
        cur ^= 1;
    }

    // write unnormalized partial + (m,l)
    const size_t pbase = ((size_t)(b * 32 + jq) * NCH + ch) * 64;
    const int q = wave * 16 + lr;
    if (lg == 0) {
        float2 v; v.x = m_r; v.y = l_r;
        ml_part[pbase + q] = v;
    }
    #pragma unroll
    for (int hf = 0; hf < 8; ++hf) {
        ushort4 hv;
        hv.x = cvt_bf16(o[hf][0]);
        hv.y = cvt_bf16(o[hf][1]);
        hv.z = cvt_bf16(o[hf][2]);
        hv.w = cvt_bf16(o[hf][3]);
        *(ushort4*)(o_part + (pbase + q) * HD + hf * 16 + 4 * lg) = hv;
    }
}

// ---------------- Stage 3: combine partials ---------------------------------------
// grid = 1024; block = 16 rows x 16 lanes/row (8 cols each).
__global__ __launch_bounds__(256) void combine_kernel(
    const ushort* __restrict__ o_part,
    const float2* __restrict__ ml_part,
    float* __restrict__ out, int cts, int NCH)
{
    const int tid = threadIdx.x;
    const int R   = blockIdx.x * 16 + (tid >> 4);    // global q-row 0..16383
    const int c16 = tid & 15;
    const int b  = R >> 11;
    const int rq = R & 2047;
    const int jq = rq >> 6;
    const int r  = rq & 63;
    const int nch = (jq >> cts) + 1;

    const size_t mlbase = ((size_t)(b * 32 + jq) * NCH) * 64 + r;

    float M = -1e30f;
    for (int c = 0; c < nch; ++c)
        M = fmaxf(M, ml_part[mlbase + (size_t)c * 64].x);
    float L = 0.0f;
    for (int c = 0; c < nch; ++c) {
        float2 v = ml_part[mlbase + (size_t)c * 64];
        L += v.y * __expf(v.x - M);
    }
    const float invL = 1.0f / L;

    float acc[8];
    #pragma unroll
    for (int k = 0; k < 8; ++k) acc[k] = 0.0f;

    for (int c = 0; c < nch; ++c) {
        float2 v = ml_part[mlbase + (size_t)c * 64];
        float sc = __expf(v.x - M) * invL;
        s8v pv = *(const s8v*)(o_part + (mlbase + (size_t)c * 64) * HD + c16 * 8);
        #pragma unroll
        for (int j = 0; j < 8; ++j) {
            union { uint32_t u; float f; } cv;
            cv.u = ((uint32_t)(ushort)pv[j]) << 16;
            acc[j] += cv.f * sc;
        }
    }

    float* po = out + (size_t)R * HD + c16 * 8;
    *(float4*)(po)     = make_float4(acc[0], acc[1], acc[2], acc[3]);
    *(float4*)(po + 4) = make_float4(acc[4], acc[5], acc[6], acc[7]);
}

extern "C" void kernel_launch(void* const* d_in, const int* in_sizes, int n_in,
                              void* d_out, int out_size, void* d_ws, size_t ws_size,
                              hipStream_t stream) {
    const float* x  = (const float*)d_in[0];
    const float* Wk = (const float*)d_in[1];
    const float* Wq = (const float*)d_in[2];
    const float* Wv = (const float*)d_in[3];

    const size_t qkv_elems = (size_t)BATCH * SEQ * HD;   // 2,097,152
    const size_t wb_elems  = (size_t)384 * EMB;          // 393,216
    ushort* Kg  = (ushort*)d_ws;
    ushort* Qg  = Kg + qkv_elems;
    ushort* VTg = Qg + qkv_elems;
    float*  outp = (float*)d_out;

    int cts = 2, NCH = 8;     // chunk = 4 kv-tiles (256 cols)
    {
        size_t rows = (size_t)BATCH * 32 * NCH * 64;
        size_t need = 3 * qkv_elems * sizeof(ushort)
                    + rows * (HD * sizeof(ushort) + sizeof(float2))
                    + wb_elems * sizeof(ushort);
        if (ws_size < need) { cts = 3; NCH = 4; }
    }
    size_t part_rows = (size_t)BATCH * 32 * NCH * 64;
    ushort* o_part  = VTg + qkv_elems;
    float2* ml_part = (float2*)(o_part + part_rows * HD);
    ushort* Wb      = (ushort*)(ml_part + part_rows);

    // triangular slot count: G groups of (1<<cts) jq's, group g has g+1 chunks
    const int G = 32 >> cts;
    const int slots = (1 << cts) * G * (G + 1) / 2;      // 144 (cts=2) / 80 (cts=3)

    wcvt_kernel<<<384, 256, 0, stream>>>(Wk, Wq, Wv, Wb);
    qkv_kernel<<<256, 512, 0, stream>>>(x, Wb, Kg, Qg, VTg);
    dim3 g2(slots, BATCH);
    attn_kernel<<<g2, 256, 0, stream>>>(Qg, Kg, VTg, o_part, ml_part, cts, NCH);
    combine_kernel<<<1024, 256, 0, stream>>>(o_part, ml_part, outp, cts, NCH);
}

// Round 10
// 82.485 us; speedup vs baseline: 1.0238x; 1.0033x over previous
//
#include <hip/hip_runtime.h>
#include <hip/hip_bf16.h>
#include <stdint.h>

#define BATCH 8
#define SEQ   2048
#define EMB   1024
#define HD    128

typedef __attribute__((ext_vector_type(8))) short  s8v;
typedef __attribute__((ext_vector_type(4))) float  f4v;

__device__ __forceinline__ ushort cvt_bf16(float f) {
    union { float f; uint32_t u; } v; v.f = f;
    uint32_t r = v.u + 0x7FFFu + ((v.u >> 16) & 1u);
    return (ushort)(r >> 16);
}

__device__ __forceinline__ uint32_t pack_bf16(float lo, float hi) {
    return ((uint32_t)cvt_bf16(hi) << 16) | (uint32_t)cvt_bf16(lo);
}

__device__ __forceinline__ f4v mfma16(s8v a, s8v b, f4v c) {
    return __builtin_amdgcn_mfma_f32_16x16x32_bf16(a, b, c, 0, 0, 0);
}

__device__ __forceinline__ uint32_t bperm(int idx, uint32_t v) {
    return (uint32_t)__builtin_amdgcn_ds_bpermute(idx, (int)v);
}

// async global->LDS DMA, 16B per lane; LDS dest = wave-uniform base + lane*16
__device__ __forceinline__ void gl_lds16(const void* g, void* l) {
    __builtin_amdgcn_global_load_lds(
        (const __attribute__((address_space(1))) void*)g,
        (__attribute__((address_space(3))) void*)l, 16, 0, 0);
}

// 8 f32 -> 8 bf16 packed (v_cvt_pk_bf16_f32)
__device__ __forceinline__ s8v cvt8(float4 a, float4 b) {
    union { s8v h; __hip_bfloat162 p[4]; } u;
    u.p[0] = __float22bfloat162_rn(make_float2(a.x, a.y));
    u.p[1] = __float22bfloat162_rn(make_float2(a.z, a.w));
    u.p[2] = __float22bfloat162_rn(make_float2(b.x, b.y));
    u.p[3] = __float22bfloat162_rn(make_float2(b.z, b.w));
    return u.h;
}

// ---------------- Stage 0: W -> bf16 concat [384][1024] ----------------------------
__global__ __launch_bounds__(256) void wcvt_kernel(
    const float* __restrict__ Wk, const float* __restrict__ Wq,
    const float* __restrict__ Wv, ushort* __restrict__ Wb)
{
    const int row = blockIdx.x;                 // 0..383
    const float* __restrict__ src =
        (row < 128) ? Wk + (size_t)row * EMB :
        (row < 256) ? Wq + (size_t)(row - 128) * EMB :
                      Wv + (size_t)(row - 256) * EMB;
    const int c = threadIdx.x << 2;
    float4 f = *(const float4*)(src + c);
    ushort4 h;
    h.x = cvt_bf16(f.x); h.y = cvt_bf16(f.y);
    h.z = cvt_bf16(f.z); h.w = cvt_bf16(f.w);
    *(ushort4*)(Wb + (size_t)row * EMB + c) = h;
}

// ---------------- Stage 1: QKV projection (r9 pipeline, VGPR budget fixed) ---------
// grid = 256 (128 M-tiles x 2 N-halves), 512 thr (8 waves, 2m x 4n, wave 64x48).
// BK=64; W panel (192x64) via swizzled global_load_lds dbuf; x tile (128x64)
// via reg->cvt->swizzled ds_write dbuf. One barrier per k-step. LDS 80 KB ->
// 2 blocks/CU. __launch_bounds__(512,4): 4 waves/EU -> VGPR cap 128 (r9's
// unbounded version got 64 VGPRs -> fragment reloads serialized every MFMA).
__global__ __launch_bounds__(512, 4) void qkv_kernel(
    const float* __restrict__ x,
    const ushort* __restrict__ Wb,     // [384][1024] bf16 (K|Q|V)
    ushort* __restrict__ Kg,           // [B*T][128] bf16
    ushort* __restrict__ Qg,           // [B*T][128] bf16
    ushort* __restrict__ VTg)          // [B][128][T] bf16 (transposed)
{
    // bid = (mt&7) + 8*(2*(mt>>3) + nt) -> same XCD for a tile's 2 blocks
    const int bid  = blockIdx.x;
    const int rest = bid >> 3;
    const int nt   = rest & 1;
    const int mt   = ((rest >> 1) << 3) | (bid & 7);
    const int m0 = mt * 128;
    const int n0 = nt * 192;

    __shared__ ushort Asm[2][128 * 64];   // x tile, swizzled storage (16 KB each)
    __shared__ ushort Bsm[2][192 * 64];   // W panel, swizzled storage (24 KB each)

    const int tid  = threadIdx.x;
    const int lane = tid & 63;
    const int wave = tid >> 6;
    const int wm = wave >> 2, wn = wave & 3;
    const int lr = lane & 15, lg = lane >> 4;

    f4v acc[4][3] = {};

    // B DMA source pointers (inverse-swizzled): 3 chunks of 1KB per wave
    const char* gB[3];
    #pragma unroll
    for (int c = 0; c < 3; ++c) {
        int cc  = wave * 3 + c;
        int row = n0 + cc * 8 + (lane >> 3);        // row&7 == lane>>3
        int cg  = (lane & 7) ^ (lane >> 3);         // swizzled col granule
        gB[c] = (const char*)Wb + (size_t)row * (EMB * 2) + cg * 16;
    }
    // x: thread covers row tid>>2, 16 f32 at col (tid&3)*16
    const int ar = tid >> 2, aq = tid & 3;
    const float* xp = x + (size_t)(m0 + ar) * EMB + aq * 16;
    const int aw0 = ar * 128 + ((((aq << 1))     ^ (ar & 7)) << 4);
    const int aw1 = ar * 128 + ((((aq << 1) | 1) ^ (ar & 7)) << 4);

    // prologue: stage k-step 0 into buf 0
    #pragma unroll
    for (int c = 0; c < 3; ++c)
        gl_lds16(gB[c], (char*)(&Bsm[0][0]) + ((wave * 3 + c) << 10));
    {
        float4 f0 = *(const float4*)(xp);
        float4 f1 = *(const float4*)(xp + 4);
        float4 f2 = *(const float4*)(xp + 8);
        float4 f3 = *(const float4*)(xp + 12);
        *(s8v*)((char*)(&Asm[0][0]) + aw0) = cvt8(f0, f1);
        *(s8v*)((char*)(&Asm[0][0]) + aw1) = cvt8(f2, f3);
    }
    __syncthreads();

    int cur = 0;
    for (int st = 0; st < 16; ++st) {
        const bool more = (st + 1 < 16);
        float4 f0, f1, f2, f3;
        if (more) {
            #pragma unroll
            for (int c = 0; c < 3; ++c) {
                gB[c] += 128;                        // next 64 cols * 2B
                gl_lds16(gB[c], (char*)(&Bsm[cur ^ 1][0]) + ((wave * 3 + c) << 10));
            }
            const float* xn = xp + (st + 1) * 64;
            f0 = *(const float4*)(xn);
            f1 = *(const float4*)(xn + 4);
            f2 = *(const float4*)(xn + 8);
            f3 = *(const float4*)(xn + 12);
        }

        const char* Ab = (const char*)(&Asm[cur][0]);
        const char* Bb = (const char*)(&Bsm[cur][0]);
        #pragma unroll
        for (int kk = 0; kk < 2; ++kk) {
            s8v af[4], bf[3];
            #pragma unroll
            for (int i = 0; i < 4; ++i) {
                int r = 64 * wm + 16 * i + lr;
                af[i] = *(const s8v*)(Ab + r * 128 + ((((kk << 2) + lg) ^ (r & 7)) << 4));
            }
            #pragma unroll
            for (int j = 0; j < 3; ++j) {
                int r = 48 * wn + 16 * j + lr;
                bf[j] = *(const s8v*)(Bb + r * 128 + ((((kk << 2) + lg) ^ (r & 7)) << 4));
            }
            #pragma unroll
            for (int i = 0; i < 4; ++i)
                #pragma unroll
                for (int j = 0; j < 3; ++j)
                    acc[i][j] = mfma16(af[i], bf[j], acc[i][j]);
        }

        if (more) {
            char* An = (char*)(&Asm[cur ^ 1][0]);
            *(s8v*)(An + aw0) = cvt8(f0, f1);
            *(s8v*)(An + aw1) = cvt8(f2, f3);
        }
        __syncthreads();    // drains B-DMA (vmcnt) + A ds_writes; buffers flip
        cur ^= 1;
    }

    const int b  = m0 >> 11;
    const int tb = m0 & 2047;
    #pragma unroll
    for (int j = 0; j < 3; ++j) {
        const int n   = n0 + 48 * wn + 16 * j + lr;
        const int sel = n >> 7;                      // 0:K 1:Q 2:V
        const int h   = n & 127;
        if (sel < 2) {
            ushort* __restrict__ outp = sel ? Qg : Kg;
            #pragma unroll
            for (int i = 0; i < 4; ++i)
                #pragma unroll
                for (int reg = 0; reg < 4; ++reg) {
                    int m = m0 + 64 * wm + 16 * i + 4 * lg + reg;
                    outp[(size_t)m * HD + h] = cvt_bf16(acc[i][j][reg]);
                }
        } else {
            #pragma unroll
            for (int i = 0; i < 4; ++i) {
                int t = tb + 64 * wm + 16 * i + 4 * lg;
                ushort4 hv;
                hv.x = cvt_bf16(acc[i][j][0]);
                hv.y = cvt_bf16(acc[i][j][1]);
                hv.z = cvt_bf16(acc[i][j][2]);
                hv.w = cvt_bf16(acc[i][j][3]);
                *(ushort4*)(VTg + ((size_t)b * HD + h) * SEQ + t) = hv;
            }
        }
    }
}

// ---------------- Stage 2: flash attention, split-KV, dbuf gload_lds ---------------
// grid = (tri_slots, BATCH). Exact triangular decomposition; no dead blocks.
// Double-buffered K/V via global_load_lds + XOR swizzle; 1 barrier per tile.
__global__ __launch_bounds__(256) void attn_kernel(
    const ushort* __restrict__ Qg,
    const ushort* __restrict__ Kg,
    const ushort* __restrict__ VTg,
    ushort* __restrict__ o_part,     // [B*32*NCH*64][128] bf16, unnormalized
    float2* __restrict__ ml_part,    // [B*32*NCH*64] (m,l)
    int cts, int NCH)
{
    // decode triangular slot -> (jq, ch)
    int s = blockIdx.x, g = 0;
    while (s >= ((g + 1) << cts)) { s -= (g + 1) << cts; ++g; }
    int q2 = 0;
    while (s >= g + 1) { s -= g + 1; ++q2; }
    const int jq = (g << cts) + q2;
    const int ch = s;
    const int b  = blockIdx.y;
    const int t0 = ch << cts;
    const int t1 = min(t0 + (1 << cts), jq + 1);

    const int tid  = threadIdx.x;
    const int lane = tid & 63;
    const int wave = tid >> 6;
    const int lr = lane & 15, lg = lane >> 4;
    const int xsw = (lr & 7) << 4;

    __shared__ ushort kl[2][64 * 128];   // [s][d] linear, swizzled storage
    __shared__ ushort vl[2][128 * 64];   // [h][s] linear, swizzled storage

    const ushort* __restrict__ Qb = Qg  + (size_t)b * SEQ * HD;
    const ushort* __restrict__ Kb = Kg  + (size_t)b * SEQ * HD;
    const ushort* __restrict__ Vb = VTg + (size_t)b * HD * SEQ;

    // staging source pointers (inverse-swizzled so linear DMA lands swizzled)
    const char* gK[4];
    const char* gV[4];
    #pragma unroll
    for (int c = 0; c < 4; ++c) {
        int cc = wave * 4 + c;
        {   int row  = cc * 4 + (lane >> 4);                 // K: 4 rows/call
            int colb = ((lane & 15) << 4) ^ ((row & 7) << 4);
            gK[c] = (const char*)Kb + (size_t)(t0 * 64 + row) * 256 + colb; }
        {   int row  = cc * 8 + (lane >> 3);                 // V: 8 rows/call
            int colb = ((lane & 7) << 4) ^ ((row & 7) << 4);
            gV[c] = (const char*)Vb + (size_t)row * (SEQ * 2)
                    + (size_t)t0 * 128 + colb; }
    }

    const int qw    = jq * 64 + wave * 16;
    const int q_abs = qw + lr;

    s8v qf[4];
    #pragma unroll
    for (int f = 0; f < 4; ++f)
        qf[f] = *(const s8v*)(Qb + (size_t)(qw + lr) * HD + 32 * f + 8 * lg);

    f4v o[8] = {};
    float m_r = -1e30f, l_r = 0.0f;

    // prologue: stage tile t0 into buf 0
    #pragma unroll
    for (int c = 0; c < 4; ++c) {
        gl_lds16(gK[c], (char*)(&kl[0][0]) + ((wave * 4 + c) << 10));
        gl_lds16(gV[c], (char*)(&vl[0][0]) + ((wave * 4 + c) << 10));
        gK[c] += 64 * 256;
        gV[c] += 128;
    }
    __syncthreads();

    const int i0 = ((2 * (lg & 1)) * 16 + lr) << 2;
    const int i1 = ((2 * (lg & 1) + 1) * 16 + lr) << 2;
    const bool hi = (lg >= 2);

    int cur = 0;
    for (int st = t0; st < t1; ++st) {
        if (st + 1 < t1) {                       // issue next-tile DMA (T3/T4)
            char* kb = (char*)(&kl[cur ^ 1][0]);
            char* vb = (char*)(&vl[cur ^ 1][0]);
            #pragma unroll
            for (int c = 0; c < 4; ++c) {
                gl_lds16(gK[c], kb + ((wave * 4 + c) << 10));
                gl_lds16(gV[c], vb + ((wave * 4 + c) << 10));
                gK[c] += 64 * 256;
                gV[c] += 128;
            }
        }
        const int s0 = st * 64;
        const char* klb = (const char*)(&kl[cur][0]);
        const char* vlb = (const char*)(&vl[cur][0]);

        // QK^T (swapped): lane owns q-col q_abs, holds s rows
        f4v sc[4] = {};
        #pragma unroll
        for (int sf = 0; sf < 4; ++sf)
            #pragma unroll
            for (int kf = 0; kf < 4; ++kf) {
                s8v kfr = *(const s8v*)(klb + ((sf * 16 + lr) << 8)
                                        + ((kf * 64 + lg * 16) ^ xsw));
                sc[sf] = mfma16(kfr, qf[kf], sc[sf]);
            }

        float p[4][4];
        const bool diag = (st == jq);
        #pragma unroll
        for (int sf = 0; sf < 4; ++sf)
            #pragma unroll
            for (int reg = 0; reg < 4; ++reg) {
                float v = sc[sf][reg] * 0.03125f;          // C^-0.5 = 1/32
                if (diag && (s0 + sf * 16 + 4 * lg + reg) > q_abs) v = -1e30f;
                p[sf][reg] = v;
            }

        // online softmax: in-lane (16) + 2 shuffles across lg quads
        float pm = p[0][0];
        #pragma unroll
        for (int sf = 0; sf < 4; ++sf)
            #pragma unroll
            for (int reg = 0; reg < 4; ++reg) pm = fmaxf(pm, p[sf][reg]);
        pm = fmaxf(pm, __shfl_xor(pm, 16));
        pm = fmaxf(pm, __shfl_xor(pm, 32));
        const float mnew = fmaxf(m_r, pm);
        const float fac  = __expf(m_r - mnew);
        m_r = mnew;

        float ls = 0.0f;
        #pragma unroll
        for (int sf = 0; sf < 4; ++sf)
            #pragma unroll
            for (int reg = 0; reg < 4; ++reg) {
                p[sf][reg] = __expf(p[sf][reg] - mnew);
                ls += p[sf][reg];
            }
        ls += __shfl_xor(ls, 16);
        ls += __shfl_xor(ls, 32);
        l_r = l_r * fac + ls;
        #pragma unroll
        for (int hf = 0; hf < 8; ++hf) o[hf] *= fac;

        // pack P -> bf16 pairs; redistribute to PV B-fragments via bpermute
        uint32_t pk[4][2];
        #pragma unroll
        for (int sf = 0; sf < 4; ++sf) {
            pk[sf][0] = pack_bf16(p[sf][0], p[sf][1]);
            pk[sf][1] = pack_bf16(p[sf][2], p[sf][3]);
        }

        #pragma unroll
        for (int s2 = 0; s2 < 2; ++s2) {
            uint32_t a0 = bperm(i0, pk[2 * s2][0]);
            uint32_t a1 = bperm(i0, pk[2 * s2][1]);
            uint32_t a2 = bperm(i1, pk[2 * s2][0]);
            uint32_t a3 = bperm(i1, pk[2 * s2][1]);
            uint32_t b0 = bperm(i0, pk[2 * s2 + 1][0]);
            uint32_t b1 = bperm(i0, pk[2 * s2 + 1][1]);
            uint32_t b2 = bperm(i1, pk[2 * s2 + 1][0]);
            uint32_t b3 = bperm(i1, pk[2 * s2 + 1][1]);
            union { int4 i; s8v h; } pb;
            pb.i.x = (int)(hi ? b0 : a0);
            pb.i.y = (int)(hi ? b1 : a1);
            pb.i.z = (int)(hi ? b2 : a2);
            pb.i.w = (int)(hi ? b3 : a3);
            #pragma unroll
            for (int hf = 0; hf < 8; ++hf) {
                s8v vf = *(const s8v*)(vlb + ((hf * 16 + lr) << 7)
                                       + ((s2 * 64 + lg * 16) ^ xsw));
                o[hf] = mfma16(vf, pb.h, o[hf]);
            }
        }

        __syncthreads();     // drains next-tile DMA (vmcnt) + all LDS reads
        cur ^= 1;
    }

    // write unnormalized partial + (m,l)
    const size_t pbase = ((size_t)(b * 32 + jq) * NCH + ch) * 64;
    const int q = wave * 16 + lr;
    if (lg == 0) {
        float2 v; v.x = m_r; v.y = l_r;
        ml_part[pbase + q] = v;
    }
    #pragma unroll
    for (int hf = 0; hf < 8; ++hf) {
        ushort4 hv;
        hv.x = cvt_bf16(o[hf][0]);
        hv.y = cvt_bf16(o[hf][1]);
        hv.z = cvt_bf16(o[hf][2]);
        hv.w = cvt_bf16(o[hf][3]);
        *(ushort4*)(o_part + (pbase + q) * HD + hf * 16 + 4 * lg) = hv;
    }
}

// ---------------- Stage 3: combine partials ---------------------------------------
// grid = 1024; block = 16 rows x 16 lanes/row (8 cols each).
__global__ __launch_bounds__(256) void combine_kernel(
    const ushort* __restrict__ o_part,
    const float2* __restrict__ ml_part,
    float* __restrict__ out, int cts, int NCH)
{
    const int tid = threadIdx.x;
    const int R   = blockIdx.x * 16 + (tid >> 4);    // global q-row 0..16383
    const int c16 = tid & 15;
    const int b  = R >> 11;
    const int rq = R & 2047;
    const int jq = rq >> 6;
    const int r  = rq & 63;
    const int nch = (jq >> cts) + 1;

    const size_t mlbase = ((size_t)(b * 32 + jq) * NCH) * 64 + r;

    float M = -1e30f;
    for (int c = 0; c < nch; ++c)
        M = fmaxf(M, ml_part[mlbase + (size_t)c * 64].x);
    float L = 0.0f;
    for (int c = 0; c < nch; ++c) {
        float2 v = ml_part[mlbase + (size_t)c * 64];
        L += v.y * __expf(v.x - M);
    }
    const float invL = 1.0f / L;

    float acc[8];
    #pragma unroll
    for (int k = 0; k < 8; ++k) acc[k] = 0.0f;

    for (int c = 0; c < nch; ++c) {
        float2 v = ml_part[mlbase + (size_t)c * 64];
        float sc = __expf(v.x - M) * invL;
        s8v pv = *(const s8v*)(o_part + (mlbase + (size_t)c * 64) * HD + c16 * 8);
        #pragma unroll
        for (int j = 0; j < 8; ++j) {
            union { uint32_t u; float f; } cv;
            cv.u = ((uint32_t)(ushort)pv[j]) << 16;
            acc[j] += cv.f * sc;
        }
    }

    float* po = out + (size_t)R * HD + c16 * 8;
    *(float4*)(po)     = make_float4(acc[0], acc[1], acc[2], acc[3]);
    *(float4*)(po + 4) = make_float4(acc[4], acc[5], acc[6], acc[7]);
}

extern "C" void kernel_launch(void* const* d_in, const int* in_sizes, int n_in,
                              void* d_out, int out_size, void* d_ws, size_t ws_size,
                              hipStream_t stream) {
    const float* x  = (const float*)d_in[0];
    const float* Wk = (const float*)d_in[1];
    const float* Wq = (const float*)d_in[2];
    const float* Wv = (const float*)d_in[3];

    const size_t qkv_elems = (size_t)BATCH * SEQ * HD;   // 2,097,152
    const size_t wb_elems  = (size_t)384 * EMB;          // 393,216
    ushort* Kg  = (ushort*)d_ws;
    ushort* Qg  = Kg + qkv_elems;
    ushort* VTg = Qg + qkv_elems;
    float*  outp = (float*)d_out;

    int cts = 2, NCH = 8;     // chunk = 4 kv-tiles (256 cols)
    {
        size_t rows = (size_t)BATCH * 32 * NCH * 64;
        size_t need = 3 * qkv_elems * sizeof(ushort)
                    + rows * (HD * sizeof(ushort) + sizeof(float2))
                    + wb_elems * sizeof(ushort);
        if (ws_size < need) { cts = 3; NCH = 4; }
    }
    size_t part_rows = (size_t)BATCH * 32 * NCH * 64;
    ushort* o_part  = VTg + qkv_elems;
    float2* ml_part = (float2*)(o_part + part_rows * HD);
    ushort* Wb      = (ushort*)(ml_part + part_rows);

    // triangular slot count: G groups of (1<<cts) jq's, group g has g+1 chunks
    const int G = 32 >> cts;
    const int slots = (1 << cts) * G * (G + 1) / 2;      // 144 (cts=2) / 80 (cts=3)

    wcvt_kernel<<<384, 256, 0, stream>>>(Wk, Wq, Wv, Wb);
    qkv_kernel<<<256, 512, 0, stream>>>(x, Wb, Kg, Qg, VTg);
    dim3 g2(slots, BATCH);
    attn_kernel<<<g2, 256, 0, stream>>>(Qg, Kg, VTg, o_part, ml_part, cts, NCH);
    combine_kernel<<<1024, 256, 0, stream>>>(o_part, ml_part, outp, cts, NCH);
}